// Round 2
// baseline (202.655 us; speedup 1.0000x reference)
//
#include <hip/hip_runtime.h>
#include <hip/hip_bf16.h>

// EdgeDecoder: out[e] = W2 @ relu(W1 @ [z[src]; z[dst]] + b1) + b2
// Restructure: W1 = [W1a | W1b] over the concat ->
//   U[n] = W1a @ z[n], V[n] = W1b @ z[n]  (precomputed via MFMA)
//   out[e] = dot(relu(U[src]+V[dst]+b1), W2) + b2
//
// R9: R8's XCD/dst sort regressed +18us: decode is NOT locality-bound (U/V
// table is L2/L3-resident already; ~38us for 327MB = 8.6TB/s effective).
// The bound is scattered 16B lane-request throughput (~21.5M requests).
// Fix: dedup U gathers. Bucket edges by exact src (atomic cursor into
// slots[src][0..64), no scan, no order needed), then an 8-lane group loads
// U[src] ONCE into registers and streams the node's dst list, gathering
// only V. Requests 21.5M -> ~12M (-44%). Predicted decode 38 -> ~22us,
// +6us bucket overhead => dur ~125us. (Fills ~88us in-window, fixed cost.)

#define N_NODES 50000
#define N_EDGES 640000
#define H 128

#define CAP 64        // max bucketed degree (Poisson mean 12.8; P(>64) ~ 0)
#define OVF_MAX 65536 // overflow list capacity (safety net)

using bf16 = __hip_bfloat16;
typedef __attribute__((ext_vector_type(8))) short short8;  // 8 bf16, 4 VGPRs
typedef __attribute__((ext_vector_type(4))) float f32x4;   // MFMA acc

#define GLD_LDS16(g, l)                                                     \
  __builtin_amdgcn_global_load_lds(                                         \
      (const __attribute__((address_space(1))) void*)(g),                   \
      (__attribute__((address_space(3))) void*)(l), 16, 0, 0)

static __device__ __forceinline__ short bfbits(float x) {
  __hip_bfloat16 h = __float2bfloat16(x);
  return *reinterpret_cast<short*>(&h);
}

static __device__ __forceinline__ short8 pack8(float4 a, float4 b) {
  short8 r;
  r[0] = bfbits(a.x); r[1] = bfbits(a.y); r[2] = bfbits(a.z); r[3] = bfbits(a.w);
  r[4] = bfbits(b.x); r[5] = bfbits(b.y); r[6] = bfbits(b.z); r[7] = bfbits(b.w);
  return r;
}

// Tiny: Wb[o][k] (bf16, A-frag row layout) from fp32 W1. o<128 -> W1[o][k],
// o>=128 -> W1[o-128][128+k]. 4096 units of 8 elems -> 16 blocks.
__global__ __launch_bounds__(256) void w_to_bf16(const float* __restrict__ W1,
                                                 bf16* __restrict__ Wb) {
  const int u = blockIdx.x * 256 + threadIdx.x;
  const int o = u >> 4, k8 = (u & 15) * 8;
  const float4* src = reinterpret_cast<const float4*>(
      W1 + (size_t)(o & (H - 1)) * (2 * H) + (o >> 7) * H + k8);
  *reinterpret_cast<short8*>(Wb + (size_t)o * H + k8) = pack8(src[0], src[1]);
}

#define HP 136  // padded bf16 LDS row stride (272B): breaks 256B-stride conflicts

// Phase 1: block = 4 waves = one 32-node tile; wave s owns outputs
// [s*64, s*64+64). fp32 z staged via global_load_lds DMA (no VGPRs), one
// LDS pass converts to bf16 tile, frags via ds_read_b128, 32 MFMAs, then
// LDS-transposed coalesced epilogue (reusing the fp32 stage buffer).
__global__ __launch_bounds__(256) void precompute_uv(
    const float* __restrict__ z, const bf16* __restrict__ Wb,
    bf16* __restrict__ U, bf16* __restrict__ V) {
  __shared__ float ldsF[32 * H];       // 16 KB: fp32 z stage, later epilogue tile
  __shared__ bf16 ldsH[32 * HP];       // 8.5 KB: padded bf16 z tile
  const int tid = threadIdx.x;
  const int lane = tid & 63;
  const int s = tid >> 6;  // wave id = o-split 0..3
  const int l15 = lane & 15, quad = lane >> 4;
  const int nodebase = blockIdx.x * 32;

  // Stage: wave s DMAs rows [s*8, s*8+8) of the tile; 4 x 1KB contiguous.
  {
    int r0 = nodebase + s * 8;
    if (r0 > N_NODES - 8) r0 = N_NODES - 8;  // tail clamp (stores guarded)
    const float* gsrc = z + (size_t)r0 * H + lane * 4;
    float* ldst = ldsF + s * 8 * H;  // + lane*16B implicit
#pragma unroll
    for (int j = 0; j < 4; ++j) GLD_LDS16(gsrc + j * 256, ldst + j * 256);
  }

  // W-frags from global bf16 (64 KB, L2-hot) — overlaps the DMA.
  short8 wf[4][4];  // [o-tile][k-step]
#pragma unroll
  for (int t = 0; t < 4; ++t) {
    const bf16* wp = Wb + (size_t)(s * 64 + t * 16 + l15) * H + quad * 8;
#pragma unroll
    for (int q = 0; q < 4; ++q)
      wf[t][q] = *reinterpret_cast<const short8*>(wp + q * 32);
  }

  __syncthreads();  // DMA + conversion-input visible

  // Convert: thread handles 16 consecutive fp32 of row (tid>>3).
  {
    const int row = tid >> 3, off = (tid & 7) * 16;
    const float4* fp = reinterpret_cast<const float4*>(ldsF + row * H + off);
    const float4 a = fp[0], b = fp[1], c = fp[2], d = fp[3];
    *reinterpret_cast<short8*>(&ldsH[row * HP + off]) = pack8(a, b);
    *reinterpret_cast<short8*>(&ldsH[row * HP + off + 8]) = pack8(c, d);
  }
  __syncthreads();

  // z-frags from LDS + 32 back-to-back MFMAs.
  short8 zf[2][4];
#pragma unroll
  for (int m = 0; m < 2; ++m)
#pragma unroll
    for (int q = 0; q < 4; ++q)
      zf[m][q] = *reinterpret_cast<const short8*>(
          &ldsH[(m * 16 + l15) * HP + quad * 8 + q * 32]);

  f32x4 acc[2][4] = {};
#pragma unroll
  for (int m = 0; m < 2; ++m)
#pragma unroll
    for (int t = 0; t < 4; ++t)
#pragma unroll
      for (int q = 0; q < 4; ++q)
        acc[m][t] =
            __builtin_amdgcn_mfma_f32_16x16x32_bf16(wf[t][q], zf[m][q], acc[m][t], 0, 0, 0);

  // Epilogue 1: acc -> LDS (reuse ldsF as 32 x 256 bf16, no pad). C/D layout:
  // col=l15 -> node row nl, row=quad*4+reg -> output o.
  bf16* epi = reinterpret_cast<bf16*>(ldsF);
#pragma unroll
  for (int m = 0; m < 2; ++m) {
    const int nl = m * 16 + l15;
#pragma unroll
    for (int t = 0; t < 4; ++t) {
      const int o = s * 64 + t * 16 + quad * 4;
      ushort4 st;
      st.x = (unsigned short)bfbits(acc[m][t][0]);
      st.y = (unsigned short)bfbits(acc[m][t][1]);
      st.z = (unsigned short)bfbits(acc[m][t][2]);
      st.w = (unsigned short)bfbits(acc[m][t][3]);
      *reinterpret_cast<ushort4*>(epi + nl * 256 + o) = st;
    }
  }
  __syncthreads();

  // Epilogue 2: coalesced stores; each instr = 4 node-rows x 256B contiguous.
#pragma unroll
  for (int half = 0; half < 2; ++half) {
    bf16* base = half ? V : U;
#pragma unroll
    for (int it = 0; it < 2; ++it) {
      const int nl = s * 8 + it * 4 + (lane >> 4);
      const int oc = (lane & 15) * 8;
      const short8 v = *reinterpret_cast<const short8*>(epi + nl * 256 + half * H + oc);
      const int n = nodebase + nl;
      if (n < N_NODES)
        *reinterpret_cast<short8*>(base + (size_t)n * H + oc) = v;
    }
  }
}

// ---------------- src-bucket build (no sort, no scan) ----------------------
// slots[src][0..CAP): packed (eid<<32 | dst<<16 | src). Order within a
// bucket is nondeterministic — harmless, each edge writes out[eid] once.
__global__ __launch_bounds__(256) void build_buckets(
    const int* __restrict__ eidx, int* __restrict__ cnt, int* __restrict__ ovfn,
    unsigned long long* __restrict__ slots,
    unsigned long long* __restrict__ ovfl) {
  const int e = blockIdx.x * 256 + threadIdx.x;
  if (e >= N_EDGES) return;
  const unsigned s = (unsigned)eidx[e];
  const unsigned d = (unsigned)eidx[N_EDGES + e];
  const unsigned long long p =
      ((unsigned long long)(unsigned)e << 32) | (d << 16) | s;
  const int pos = atomicAdd(&cnt[s], 1);
  if (pos < CAP) {
    slots[(size_t)s * CAP + pos] = p;
  } else {
    const int op = atomicAdd(ovfn, 1);
    if (op < OVF_MAX) ovfl[op] = p;
  }
}

static __device__ __forceinline__ void acc2(unsigned u, unsigned v,
                                            float b1lo, float b1hi,
                                            float w2lo, float w2hi, float& sum) {
  const float ulo = __uint_as_float(u << 16);
  const float uhi = __uint_as_float(u & 0xffff0000u);
  const float vlo = __uint_as_float(v << 16);
  const float vhi = __uint_as_float(v & 0xffff0000u);
  float h0 = ulo + vlo + b1lo; h0 = fmaxf(h0, 0.f);
  float h1 = uhi + vhi + b1hi; h1 = fmaxf(h1, 0.f);
  sum = fmaf(h0, w2lo, sum);
  sum = fmaf(h1, w2hi, sum);
}

static __device__ __forceinline__ float edge_sum(const uint4& a0, const uint4& a1,
                                                 const uint4& c0, const uint4& c1,
                                                 const float* b1r, const float* w2r) {
  float sum = 0.f;
  acc2(a0.x, c0.x, b1r[0],  b1r[1],  w2r[0],  w2r[1],  sum);
  acc2(a0.y, c0.y, b1r[2],  b1r[3],  w2r[2],  w2r[3],  sum);
  acc2(a0.z, c0.z, b1r[4],  b1r[5],  w2r[4],  w2r[5],  sum);
  acc2(a0.w, c0.w, b1r[6],  b1r[7],  w2r[6],  w2r[7],  sum);
  acc2(a1.x, c1.x, b1r[8],  b1r[9],  w2r[8],  w2r[9],  sum);
  acc2(a1.y, c1.y, b1r[10], b1r[11], w2r[10], w2r[11], sum);
  acc2(a1.z, c1.z, b1r[12], b1r[13], w2r[12], w2r[13], sum);
  acc2(a1.w, c1.w, b1r[14], b1r[15], w2r[14], w2r[15], sum);
  return sum;
}

// Phase 2 (CSR): 8-lane group per src node. U[src] loaded ONCE into regs
// (2 uint4/lane), then the node's dst list is streamed: per edge only the
// V row is gathered (16 lane-requests vs 32 before). Adjacent groups own
// adjacent nodes -> cnt reads and U loads are wave-coalesced. dst-tail
// loads are exec-masked (m uniform per group, partners of the 8-lane
// shfl_xor reduce share the predicate). V4 index masked to 16 bits stays
// inside the workspace even for garbage tail entries.
__global__ __launch_bounds__(256, 4) void edge_decode_csr(
    const unsigned long long* __restrict__ slots, const int* __restrict__ cnt,
    const int* __restrict__ ovfn, const unsigned long long* __restrict__ ovfl,
    const bf16* __restrict__ Ub, const bf16* __restrict__ Vb,
    const float* __restrict__ bias1, const float* __restrict__ W2,
    const float* __restrict__ bias2, float* __restrict__ out) {
  const int e8 = threadIdx.x & 7;
  const int g = (blockIdx.x * 256 + threadIdx.x) >> 3;
  const int n_groups = gridDim.x * 32;

  float b1r[16], w2r[16];
  const float4* bp = reinterpret_cast<const float4*>(bias1 + e8 * 16);
  const float4* wp = reinterpret_cast<const float4*>(W2 + e8 * 16);
#pragma unroll
  for (int q = 0; q < 4; ++q) {
    const float4 b = bp[q], wv = wp[q];
    b1r[q * 4 + 0] = b.x; b1r[q * 4 + 1] = b.y; b1r[q * 4 + 2] = b.z; b1r[q * 4 + 3] = b.w;
    w2r[q * 4 + 0] = wv.x; w2r[q * 4 + 1] = wv.y; w2r[q * 4 + 2] = wv.z; w2r[q * 4 + 3] = wv.w;
  }
  const float b2 = bias2[0];

  const uint4* U4 = reinterpret_cast<const uint4*>(Ub);  // row = 16 uint4
  const uint4* V4 = reinterpret_cast<const uint4*>(Vb);

  for (int n = g; n < N_NODES; n += n_groups) {
    const int deg = min(cnt[n], CAP);
    if (deg == 0) continue;
    const uint4* up = U4 + (size_t)n * 16 + e8 * 2;
    const uint4 u0 = up[0], u1 = up[1];
    const unsigned long long* sb = slots + (size_t)n * CAP;

    for (int j0 = 0; j0 < deg; j0 += 4) {
      const int m = deg - j0;  // >= 1; uniform within the 8-lane group
      // Fetch up to 4 packed entries (lanes 0-3 / 4-7 mirror -> 32B read).
      unsigned long long ent = 0;
      if ((e8 & 3) < m) ent = sb[j0 + (e8 & 3)];
      uint4 va[4], vb[4];
      int eid[4];
#pragma unroll
      for (int j = 0; j < 4; ++j) {
        const unsigned long long pj = __shfl(ent, (threadIdx.x & 56) | j);
        if (j < m) {
          const int dj = (int)((pj >> 16) & 0xffffu);
          eid[j] = (int)(pj >> 32);
          const uint4* vp = V4 + (size_t)dj * 16 + e8 * 2;
          va[j] = vp[0];
          vb[j] = vp[1];
        }
      }
#pragma unroll
      for (int j = 0; j < 4; ++j) {
        if (j < m) {
          float sum = edge_sum(u0, u1, va[j], vb[j], b1r, w2r);
          sum += __shfl_xor(sum, 1);
          sum += __shfl_xor(sum, 2);
          sum += __shfl_xor(sum, 4);
          if (e8 == j) out[eid[j]] = sum + b2;  // one scattered 4B store/edge
        }
      }
    }
  }

  // Overflow entries (deg > CAP; statistically zero, kept for correctness).
  const int no = min(*ovfn, OVF_MAX);
  for (int i = g; i < no; i += n_groups) {
    const unsigned long long p = ovfl[i];
    const int s = (int)(p & 0xffffu);
    const int d = (int)((p >> 16) & 0xffffu);
    const int eid0 = (int)(p >> 32);
    const uint4* up2 = U4 + (size_t)s * 16 + e8 * 2;
    const uint4* vp2 = V4 + (size_t)d * 16 + e8 * 2;
    const uint4 a0 = up2[0], a1 = up2[1], c0 = vp2[0], c1 = vp2[1];
    float sum = edge_sum(a0, a1, c0, c1, b1r, w2r);
    sum += __shfl_xor(sum, 1);
    sum += __shfl_xor(sum, 2);
    sum += __shfl_xor(sum, 4);
    if (e8 == 0) out[eid0] = sum + b2;
  }
}

extern "C" void kernel_launch(void* const* d_in, const int* in_sizes, int n_in,
                              void* d_out, int out_size, void* d_ws, size_t ws_size,
                              hipStream_t stream) {
  const float* z     = (const float*)d_in[0];
  const float* W1    = (const float*)d_in[1];
  const float* bias1 = (const float*)d_in[2];
  const float* W2    = (const float*)d_in[3];
  const float* bias2 = (const float*)d_in[4];
  const int*   eidx  = (const int*)d_in[5];
  float* out = (float*)d_out;

  bf16* U  = (bf16*)d_ws;                               // [N_NODES, H] 12.8 MB
  bf16* V  = U + (size_t)N_NODES * H;                   // [N_NODES, H] 12.8 MB
  bf16* Wb = V + (size_t)N_NODES * H;                   // [256, H] 64 KB
  unsigned long long* slots =
      (unsigned long long*)(Wb + 256 * H);              // [N_NODES, CAP] 25.6 MB
  int* cnt  = (int*)(slots + (size_t)N_NODES * CAP);    // [50048]
  int* ovfn = cnt + 50048;                              // [1] (+pad)
  unsigned long long* ovfl =
      (unsigned long long*)(cnt + 50064);               // [OVF_MAX] 512 KB

  // Bucket state rebuilt every launch (ws is poisoned between iterations).
  hipMemsetAsync(cnt, 0, 50064 * sizeof(int), stream);  // covers cnt + ovfn

  // W convert: 4096 units / 256 = 16 blocks (~1.5 us).
  hipLaunchKernelGGL(w_to_bf16, dim3(16), dim3(256), 0, stream, W1, Wb);
  // Phase 1: 1563 blocks x 4 waves; block = 32-node tile, wave = 64-output split.
  hipLaunchKernelGGL(precompute_uv, dim3((N_NODES + 31) / 32), dim3(256), 0, stream,
                     z, Wb, U, V);
  // Bucket build: 2500 blocks, 1 edge/thread (~4 us).
  hipLaunchKernelGGL(build_buckets, dim3((N_EDGES + 255) / 256), dim3(256), 0,
                     stream, eidx, cnt, ovfn, slots, ovfl);
  // Phase 2: 512 blocks = 16384 groups, ~3 nodes each.
  hipLaunchKernelGGL(edge_decode_csr, dim3(512), dim3(256), 0, stream,
                     slots, cnt, ovfn, ovfl, U, V, bias1, W2, bias2, out);
}

// Round 4
// 144.605 us; speedup vs baseline: 1.4014x; 1.4014x over previous
//
#include <hip/hip_runtime.h>
#include <hip/hip_bf16.h>

// EdgeDecoder: out[e] = W2 @ relu(W1 @ [z[src]; z[dst]] + b1) + b2
// Restructure: W1 = [W1a | W1b] over the concat ->
//   U[n] = W1a @ z[n], V[n] = W1b @ z[n]  (precomputed via MFMA)
//   out[e] = dot(relu(U[src]+V[dst]+b1), W2) + b2
//
// R11 (= R10 resubmit; R10's bench was an infra failure, kernel never ran).
// R2's counters prove decode is LATENCY x MLP bound (occ 14%, VALU 25%,
// hbm 20%, nothing saturated; R0's 36us = 0.23 lines/cyc/CU = ~200
// outstanding lines at ~900cy L3 latency). R1's locality idea was right but
// occupancy-starved (512 blocks). Fix: (dst-XCD, src-bucket) binning + R0's
// flat dependency-free decode at FULL grid (3072 blocks). V partition
// (1.6MB) L2-resident per XCD; src-bucket slot-order sweep keeps live U
// window ~2.6MB => avg gather latency ~300cy => decode ~15us. Sort cost cut
// to one scatter kernel (fixed-capacity bins + LDS-aggregated cursors,
// W-convert fused in) ~6us. Predicted total ~125us (fills ~88us fixed).

#define N_NODES 50000
#define N_EDGES 640000
#define H 128

#define NBINS 256          // 8 dst-XCD buckets x 32 src buckets
#define CAPB 3072          // slots per bin (mean 2500, +11 sigma)
#define CHUNKS_PER_BIN 12  // CAPB / 256
#define SCAT_BLOCKS 128
#define EPT 20             // 128*256*20 >= 640k
#define OVF_MAX 65536

using bf16 = __hip_bfloat16;
typedef __attribute__((ext_vector_type(8))) short short8;  // 8 bf16, 4 VGPRs
typedef __attribute__((ext_vector_type(4))) float f32x4;   // MFMA acc

#define GLD_LDS16(g, l)                                                     \
  __builtin_amdgcn_global_load_lds(                                         \
      (const __attribute__((address_space(1))) void*)(g),                   \
      (__attribute__((address_space(3))) void*)(l), 16, 0, 0)

static __device__ __forceinline__ short bfbits(float x) {
  __hip_bfloat16 h = __float2bfloat16(x);
  return *reinterpret_cast<short*>(&h);
}

static __device__ __forceinline__ short8 pack8(float4 a, float4 b) {
  short8 r;
  r[0] = bfbits(a.x); r[1] = bfbits(a.y); r[2] = bfbits(a.z); r[3] = bfbits(a.w);
  r[4] = bfbits(b.x); r[5] = bfbits(b.y); r[6] = bfbits(b.z); r[7] = bfbits(b.w);
  return r;
}

#define HP 136  // padded bf16 LDS row stride (272B): breaks 256B-stride conflicts

// Phase 1: block = 4 waves = one 32-node tile; wave s owns outputs
// [s*64, s*64+64). fp32 z staged via global_load_lds DMA, one LDS pass
// converts to bf16, frags via ds_read_b128, 32 MFMAs, LDS-transposed
// coalesced epilogue. (Unchanged from R0 — ~10us, near traffic floor.)
__global__ __launch_bounds__(256) void precompute_uv(
    const float* __restrict__ z, const bf16* __restrict__ Wb,
    bf16* __restrict__ U, bf16* __restrict__ V) {
  __shared__ float ldsF[32 * H];       // 16 KB: fp32 z stage, later epilogue tile
  __shared__ bf16 ldsH[32 * HP];       // 8.5 KB: padded bf16 z tile
  const int tid = threadIdx.x;
  const int lane = tid & 63;
  const int s = tid >> 6;  // wave id = o-split 0..3
  const int l15 = lane & 15, quad = lane >> 4;
  const int nodebase = blockIdx.x * 32;

  {
    int r0 = nodebase + s * 8;
    if (r0 > N_NODES - 8) r0 = N_NODES - 8;  // tail clamp (stores guarded)
    const float* gsrc = z + (size_t)r0 * H + lane * 4;
    float* ldst = ldsF + s * 8 * H;  // + lane*16B implicit
#pragma unroll
    for (int j = 0; j < 4; ++j) GLD_LDS16(gsrc + j * 256, ldst + j * 256);
  }

  short8 wf[4][4];  // [o-tile][k-step]
#pragma unroll
  for (int t = 0; t < 4; ++t) {
    const bf16* wp = Wb + (size_t)(s * 64 + t * 16 + l15) * H + quad * 8;
#pragma unroll
    for (int q = 0; q < 4; ++q)
      wf[t][q] = *reinterpret_cast<const short8*>(wp + q * 32);
  }

  __syncthreads();  // DMA + conversion-input visible

  {
    const int row = tid >> 3, off = (tid & 7) * 16;
    const float4* fp = reinterpret_cast<const float4*>(ldsF + row * H + off);
    const float4 a = fp[0], b = fp[1], c = fp[2], d = fp[3];
    *reinterpret_cast<short8*>(&ldsH[row * HP + off]) = pack8(a, b);
    *reinterpret_cast<short8*>(&ldsH[row * HP + off + 8]) = pack8(c, d);
  }
  __syncthreads();

  short8 zf[2][4];
#pragma unroll
  for (int m = 0; m < 2; ++m)
#pragma unroll
    for (int q = 0; q < 4; ++q)
      zf[m][q] = *reinterpret_cast<const short8*>(
          &ldsH[(m * 16 + l15) * HP + quad * 8 + q * 32]);

  f32x4 acc[2][4] = {};
#pragma unroll
  for (int m = 0; m < 2; ++m)
#pragma unroll
    for (int t = 0; t < 4; ++t)
#pragma unroll
      for (int q = 0; q < 4; ++q)
        acc[m][t] =
            __builtin_amdgcn_mfma_f32_16x16x32_bf16(wf[t][q], zf[m][q], acc[m][t], 0, 0, 0);

  bf16* epi = reinterpret_cast<bf16*>(ldsF);
#pragma unroll
  for (int m = 0; m < 2; ++m) {
    const int nl = m * 16 + l15;
#pragma unroll
    for (int t = 0; t < 4; ++t) {
      const int o = s * 64 + t * 16 + quad * 4;
      ushort4 st;
      st.x = (unsigned short)bfbits(acc[m][t][0]);
      st.y = (unsigned short)bfbits(acc[m][t][1]);
      st.z = (unsigned short)bfbits(acc[m][t][2]);
      st.w = (unsigned short)bfbits(acc[m][t][3]);
      *reinterpret_cast<ushort4*>(epi + nl * 256 + o) = st;
    }
  }
  __syncthreads();

#pragma unroll
  for (int half = 0; half < 2; ++half) {
    bf16* base = half ? V : U;
#pragma unroll
    for (int it = 0; it < 2; ++it) {
      const int nl = s * 8 + it * 4 + (lane >> 4);
      const int oc = (lane & 15) * 8;
      const short8 v = *reinterpret_cast<const short8*>(epi + nl * 256 + half * H + oc);
      const int n = nodebase + nl;
      if (n < N_NODES)
        *reinterpret_cast<short8*>(base + (size_t)n * H + oc) = v;
    }
  }
}

// ---------------- bin scatter (single pass, no hist/scan) ------------------
// key = (dst/6250)*32 + src/1563. Bin b owns sde[b*CAPB .. b*CAPB+CAPB).
// Block-aggregated reservation: LDS count -> one global atomicAdd per
// (block,bin) -> per-edge LDS cursor (global position). pos >= CAPB spills
// to overflow list (P ~ 0, +11 sigma). Entry = (eid<<32 | dst<<16 | src).
// Within-bin order nondeterministic — harmless, each edge writes out[eid]
// once. Blocks >= SCAT_BLOCKS instead convert W1 -> bf16 Wb (fused launch).
__global__ __launch_bounds__(256) void scatter_w(
    const int* __restrict__ eidx, const float* __restrict__ W1,
    bf16* __restrict__ Wb, int* __restrict__ cursors, int* __restrict__ ovfn,
    unsigned long long* __restrict__ sde,
    unsigned long long* __restrict__ ovfl) {
  if (blockIdx.x >= SCAT_BLOCKS) {  // 16 W-convert blocks
    const int u = (blockIdx.x - SCAT_BLOCKS) * 256 + threadIdx.x;
    const int o = u >> 4, k8 = (u & 15) * 8;
    const float4* src = reinterpret_cast<const float4*>(
        W1 + (size_t)(o & (H - 1)) * (2 * H) + (o >> 7) * H + k8);
    *reinterpret_cast<short8*>(Wb + (size_t)o * H + k8) = pack8(src[0], src[1]);
    return;
  }
  __shared__ int lh[NBINS];
  __shared__ int lcur[NBINS];
  const int t = threadIdx.x;
  lh[t] = 0;
  __syncthreads();
  unsigned long long ent[EPT];
  int key[EPT];
  const int base = blockIdx.x * (256 * EPT) + t;
#pragma unroll
  for (int j = 0; j < EPT; ++j) {
    const int e = base + j * 256;
    if (e < N_EDGES) {
      const unsigned s = (unsigned)eidx[e];
      const unsigned d = (unsigned)eidx[N_EDGES + e];
      ent[j] = ((unsigned long long)(unsigned)e << 32) | (d << 16) | s;
      key[j] = (int)(d / 6250u) * 32 + (int)(s / 1563u);
      atomicAdd(&lh[key[j]], 1);
    } else {
      key[j] = -1;
    }
  }
  __syncthreads();
  lcur[t] = lh[t] ? atomicAdd(&cursors[t * 16], lh[t]) : 0;
  __syncthreads();
#pragma unroll
  for (int j = 0; j < EPT; ++j) {
    if (key[j] >= 0) {
      const int pos = atomicAdd(&lcur[key[j]], 1);  // global position in bin
      if (pos < CAPB) {
        sde[(size_t)key[j] * CAPB + pos] = ent[j];
      } else {
        const int op = atomicAdd(ovfn, 1);
        if (op < OVF_MAX) ovfl[op] = ent[j];
      }
    }
  }
}

static __device__ __forceinline__ void acc2(unsigned u, unsigned v,
                                            float b1lo, float b1hi,
                                            float w2lo, float w2hi, float& sum) {
  const float ulo = __uint_as_float(u << 16);
  const float uhi = __uint_as_float(u & 0xffff0000u);
  const float vlo = __uint_as_float(v << 16);
  const float vhi = __uint_as_float(v & 0xffff0000u);
  float h0 = ulo + vlo + b1lo; h0 = fmaxf(h0, 0.f);
  float h1 = uhi + vhi + b1hi; h1 = fmaxf(h1, 0.f);
  sum = fmaf(h0, w2lo, sum);
  sum = fmaf(h1, w2hi, sum);
}

static __device__ __forceinline__ float edge_sum(const uint4& a0, const uint4& a1,
                                                 const uint4& c0, const uint4& c1,
                                                 const float* b1r, const float* w2r) {
  float sum = 0.f;
  acc2(a0.x, c0.x, b1r[0],  b1r[1],  w2r[0],  w2r[1],  sum);
  acc2(a0.y, c0.y, b1r[2],  b1r[3],  w2r[2],  w2r[3],  sum);
  acc2(a0.z, c0.z, b1r[4],  b1r[5],  w2r[4],  w2r[5],  sum);
  acc2(a0.w, c0.w, b1r[6],  b1r[7],  w2r[6],  w2r[7],  sum);
  acc2(a1.x, c1.x, b1r[8],  b1r[9],  w2r[8],  w2r[9],  sum);
  acc2(a1.y, c1.y, b1r[10], b1r[11], w2r[10], w2r[11], sum);
  acc2(a1.z, c1.z, b1r[12], b1r[13], w2r[12], w2r[13], sum);
  acc2(a1.w, c1.w, b1r[14], b1r[15], w2r[14], w2r[15], sum);
  return sum;
}

// One wave processes up to 64 packed edges (R0's proven flat structure:
// 8-lane group per edge, gathers batched 4 edges deep = 16 outstanding
// uint4/lane, zero serial chains). Masked tail lanes gather row 0 (safe,
// in-workspace) and skip the store.
static __device__ __forceinline__ void decode64(
    const unsigned long long* __restrict__ ents, int mvalid,
    const uint4* __restrict__ U4, const uint4* __restrict__ V4,
    const float* b1r, const float* w2r, float b2, float* __restrict__ out,
    int lane, int e8) {
  const bool valid = lane < mvalid;
  const unsigned long long v = valid ? ents[lane] : 0ull;
  const int src = (int)(v & 0xffffu);
  const int dst = (int)((v >> 16) & 0xffffu);
  const int eid = (int)(v >> 32);

  float res = 0.f;
#pragma unroll
  for (int half = 0; half < 2; ++half) {
    uint4 ua[4], ub[4], va[4], vb[4];
#pragma unroll
    for (int j = 0; j < 4; ++j) {
      const int i = half * 4 + j;
      const int sl = (lane & 56) | i;
      const int s_i = __shfl(src, sl);
      const int d_i = __shfl(dst, sl);
      const uint4* up = U4 + (size_t)s_i * 16 + e8 * 2;
      const uint4* vp = V4 + (size_t)d_i * 16 + e8 * 2;
      ua[j] = up[0]; ub[j] = up[1];
      va[j] = vp[0]; vb[j] = vp[1];
    }
#pragma unroll
    for (int j = 0; j < 4; ++j) {
      const int i = half * 4 + j;
      float sum = edge_sum(ua[j], ub[j], va[j], vb[j], b1r, w2r);
      sum += __shfl_xor(sum, 1);
      sum += __shfl_xor(sum, 2);
      sum += __shfl_xor(sum, 4);
      if (e8 == i) res = sum + b2;
    }
  }
  if (valid) out[eid] = res;  // one scattered 4B store per edge
}

// Phase 2: grid 3072 = 8 XCDs x 32 src-buckets x 12 chunk-slots. blockIdx&7
// -> XCD (round-robin dispatch heuristic): the bin's V rows live in this
// XCD's 1.6MB L2 partition. slot>>3 ascends through src-buckets, so the
// concurrently-resident blocks share a ~2.6MB U window. Empty chunk-slots
// exit immediately. Overflow entries (P~0) swept by wave-strided tail.
__global__ __launch_bounds__(256, 4) void edge_decode_sorted(
    const unsigned long long* __restrict__ sde, const int* __restrict__ cursors,
    const int* __restrict__ ovfn, const unsigned long long* __restrict__ ovfl,
    const bf16* __restrict__ Ub, const bf16* __restrict__ Vb,
    const float* __restrict__ bias1, const float* __restrict__ W2,
    const float* __restrict__ bias2, float* __restrict__ out) {
  const int lane = threadIdx.x & 63;
  const int e8 = lane & 7;
  const int w = threadIdx.x >> 6;

  float b1r[16], w2r[16];
  const float4* bp = reinterpret_cast<const float4*>(bias1 + e8 * 16);
  const float4* wp = reinterpret_cast<const float4*>(W2 + e8 * 16);
#pragma unroll
  for (int q = 0; q < 4; ++q) {
    const float4 b = bp[q], wv = wp[q];
    b1r[q * 4 + 0] = b.x; b1r[q * 4 + 1] = b.y; b1r[q * 4 + 2] = b.z; b1r[q * 4 + 3] = b.w;
    w2r[q * 4 + 0] = wv.x; w2r[q * 4 + 1] = wv.y; w2r[q * 4 + 2] = wv.z; w2r[q * 4 + 3] = wv.w;
  }
  const float b2 = bias2[0];

  const uint4* U4 = reinterpret_cast<const uint4*>(Ub);  // row = 16 uint4
  const uint4* V4 = reinterpret_cast<const uint4*>(Vb);

  const int xcd = blockIdx.x & 7;
  const int slot = blockIdx.x >> 3;           // 0..383, ascends src-buckets
  const int sb = slot / CHUNKS_PER_BIN;       // 0..31
  const int k = slot - sb * CHUNKS_PER_BIN;   // 0..11
  const int bin = (xcd << 5) + sb;
  const int c = min(cursors[bin * 16], CAPB);
  const int base = k * 256 + w * 64;          // this wave's 64-edge window
  if (base < c)
    decode64(sde + (size_t)bin * CAPB + base, min(64, c - base), U4, V4, b1r,
             w2r, b2, out, lane, e8);

  // Overflow tail (statistically empty; one scalar load + branch).
  const int no = min(*ovfn, OVF_MAX);
  for (int b0 = (blockIdx.x * 4 + w) * 64; b0 < no; b0 += (int)gridDim.x * 4 * 64)
    decode64(ovfl + b0, min(64, no - b0), U4, V4, b1r, w2r, b2, out, lane, e8);
}

extern "C" void kernel_launch(void* const* d_in, const int* in_sizes, int n_in,
                              void* d_out, int out_size, void* d_ws, size_t ws_size,
                              hipStream_t stream) {
  const float* z     = (const float*)d_in[0];
  const float* W1    = (const float*)d_in[1];
  const float* bias1 = (const float*)d_in[2];
  const float* W2    = (const float*)d_in[3];
  const float* bias2 = (const float*)d_in[4];
  const int*   eidx  = (const int*)d_in[5];
  float* out = (float*)d_out;

  bf16* U  = (bf16*)d_ws;                               // [N_NODES, H] 12.8 MB
  bf16* V  = U + (size_t)N_NODES * H;                   // [N_NODES, H] 12.8 MB
  bf16* Wb = V + (size_t)N_NODES * H;                   // [256, H] 64 KB
  unsigned long long* sde =
      (unsigned long long*)(Wb + 256 * H);              // [NBINS*CAPB] 6.3 MB
  int* cursors = (int*)(sde + (size_t)NBINS * CAPB);    // [NBINS*16] 16 KB
  int* ovfn    = cursors + NBINS * 16;                  // [1] (+pad to 16)
  unsigned long long* ovfl =
      (unsigned long long*)(cursors + NBINS * 16 + 16); // [OVF_MAX] 512 KB

  // Cursor state rebuilt every launch (ws is poisoned between iterations).
  hipMemsetAsync(cursors, 0, (NBINS * 16 + 16) * sizeof(int), stream);

  // Scatter (128 blocks) + fused W-convert (16 blocks): ~6 us.
  hipLaunchKernelGGL(scatter_w, dim3(SCAT_BLOCKS + 16), dim3(256), 0, stream,
                     eidx, W1, Wb, cursors, ovfn, sde, ovfl);
  // Phase 1: 1563 blocks x 4 waves; block = 32-node tile, wave = 64-output split.
  hipLaunchKernelGGL(precompute_uv, dim3((N_NODES + 31) / 32), dim3(256), 0, stream,
                     z, Wb, U, V);
  // Phase 2: 3072 blocks = 8 XCDs x 32 buckets x 12 chunk-slots.
  hipLaunchKernelGGL(edge_decode_sorted, dim3(8 * 32 * CHUNKS_PER_BIN), dim3(256),
                     0, stream, sde, cursors, ovfn, ovfl, U, V, bias1, W2, bias2,
                     out);
}

// Round 5
// 139.089 us; speedup vs baseline: 1.4570x; 1.0397x over previous
//
#include <hip/hip_runtime.h>
#include <hip/hip_bf16.h>

// EdgeDecoder: out[e] = W2 @ relu(W1 @ [z[src]; z[dst]] + b1) + b2
// Restructure: W1 = [W1a | W1b] over the concat ->
//   U[n] = W1a @ z[n] + b1/2, V[n] = W1b @ z[n] + b1/2   (precomputed, MFMA)
//   out[e] = dot(relu(U[src]+V[dst]), W2) + b2
//
// R12: R4 proved XCD-binning nets 0 (decode_sorted == decode_flat == 36.5us;
// live U-window ~8MB/XCD >> 4MB L2 at full grid; R1 showed locality works
// per-wave but the parallelism<->window frontier always nets ~= R0). Sort
// dropped. New theory: flat decode is CONCURRENCY-limited below the L3 BW
// ceiling — R0's decode compiled to VGPR=60 (b1r+w2r=32 regs alone), so only
// ~5 of 16 gathers were actually in flight per wave; 327MB/36.5us = 9.0TB/s
// matches ~96 lines/CU at ~400cy L3 latency. Fix: (a) fold b1/2 into U,V at
// precompute (-16 VGPR, -13% decode VALU), (b) issue all 16 gathers per
// half then sched_barrier(0) so the compiler cannot sink loads into the
// compute loop (forces 16 in flight, ~100 VGPR, fits 4 waves/EU), (c) 1024
// grid-stride blocks (exactly resident, no ragged tail). Predicted: decode
// -> 22-26us, total ~122-127; if unchanged => ~9TB/s L3 ceiling confirmed,
// next step is traffic reduction via LDS U-dedup.

#define N_NODES 50000
#define N_EDGES 640000
#define H 128

using bf16 = __hip_bfloat16;
typedef __attribute__((ext_vector_type(8))) short short8;  // 8 bf16, 4 VGPRs
typedef __attribute__((ext_vector_type(4))) float f32x4;   // MFMA acc

#define GLD_LDS16(g, l)                                                     \
  __builtin_amdgcn_global_load_lds(                                         \
      (const __attribute__((address_space(1))) void*)(g),                   \
      (__attribute__((address_space(3))) void*)(l), 16, 0, 0)

static __device__ __forceinline__ short bfbits(float x) {
  __hip_bfloat16 h = __float2bfloat16(x);
  return *reinterpret_cast<short*>(&h);
}

static __device__ __forceinline__ short8 pack8(float4 a, float4 b) {
  short8 r;
  r[0] = bfbits(a.x); r[1] = bfbits(a.y); r[2] = bfbits(a.z); r[3] = bfbits(a.w);
  r[4] = bfbits(b.x); r[5] = bfbits(b.y); r[6] = bfbits(b.z); r[7] = bfbits(b.w);
  return r;
}

// Tiny: Wb[o][k] (bf16, A-frag row layout) from fp32 W1. o<128 -> W1[o][k],
// o>=128 -> W1[o-128][128+k]. 4096 units of 8 elems -> 16 blocks.
__global__ __launch_bounds__(256) void w_to_bf16(const float* __restrict__ W1,
                                                 bf16* __restrict__ Wb) {
  const int u = blockIdx.x * 256 + threadIdx.x;
  const int o = u >> 4, k8 = (u & 15) * 8;
  const float4* src = reinterpret_cast<const float4*>(
      W1 + (size_t)(o & (H - 1)) * (2 * H) + (o >> 7) * H + k8);
  *reinterpret_cast<short8*>(Wb + (size_t)o * H + k8) = pack8(src[0], src[1]);
}

#define HP 136  // padded bf16 LDS row stride (272B): breaks 256B-stride conflicts

// Phase 1: block = 4 waves = one 32-node tile; wave s owns outputs
// [s*64, s*64+64). fp32 z staged via global_load_lds DMA, one LDS pass
// converts to bf16, frags via ds_read_b128, 32 MFMAs, LDS-transposed
// coalesced epilogue. NEW: adds 0.5*b1[o] to every output before the bf16
// round, so decode can skip the bias add entirely (U+V restores b1).
__global__ __launch_bounds__(256) void precompute_uv(
    const float* __restrict__ z, const bf16* __restrict__ Wb,
    const float* __restrict__ bias1, bf16* __restrict__ U,
    bf16* __restrict__ V) {
  __shared__ float ldsF[32 * H];       // 16 KB: fp32 z stage, later epilogue tile
  __shared__ bf16 ldsH[32 * HP];       // 8.5 KB: padded bf16 z tile
  const int tid = threadIdx.x;
  const int lane = tid & 63;
  const int s = tid >> 6;  // wave id = o-split 0..3
  const int l15 = lane & 15, quad = lane >> 4;
  const int nodebase = blockIdx.x * 32;

  // Stage: wave s DMAs rows [s*8, s*8+8) of the tile; 4 x 1KB contiguous.
  {
    int r0 = nodebase + s * 8;
    if (r0 > N_NODES - 8) r0 = N_NODES - 8;  // tail clamp (stores guarded)
    const float* gsrc = z + (size_t)r0 * H + lane * 4;
    float* ldst = ldsF + s * 8 * H;  // + lane*16B implicit
#pragma unroll
    for (int j = 0; j < 4; ++j) GLD_LDS16(gsrc + j * 256, ldst + j * 256);
  }

  // W-frags from global bf16 (64 KB, L2-hot) — overlaps the DMA.
  short8 wf[4][4];  // [o-tile][k-step]
#pragma unroll
  for (int t = 0; t < 4; ++t) {
    const bf16* wp = Wb + (size_t)(s * 64 + t * 16 + l15) * H + quad * 8;
#pragma unroll
    for (int q = 0; q < 4; ++q)
      wf[t][q] = *reinterpret_cast<const short8*>(wp + q * 32);
  }

  __syncthreads();  // DMA + conversion-input visible

  // Convert: thread handles 16 consecutive fp32 of row (tid>>3).
  {
    const int row = tid >> 3, off = (tid & 7) * 16;
    const float4* fp = reinterpret_cast<const float4*>(ldsF + row * H + off);
    const float4 a = fp[0], b = fp[1], c = fp[2], d = fp[3];
    *reinterpret_cast<short8*>(&ldsH[row * HP + off]) = pack8(a, b);
    *reinterpret_cast<short8*>(&ldsH[row * HP + off + 8]) = pack8(c, d);
  }
  __syncthreads();

  // z-frags from LDS + 32 back-to-back MFMAs.
  short8 zf[2][4];
#pragma unroll
  for (int m = 0; m < 2; ++m)
#pragma unroll
    for (int q = 0; q < 4; ++q)
      zf[m][q] = *reinterpret_cast<const short8*>(
          &ldsH[(m * 16 + l15) * HP + quad * 8 + q * 32]);

  f32x4 acc[2][4] = {};
#pragma unroll
  for (int m = 0; m < 2; ++m)
#pragma unroll
    for (int t = 0; t < 4; ++t)
#pragma unroll
      for (int q = 0; q < 4; ++q)
        acc[m][t] =
            __builtin_amdgcn_mfma_f32_16x16x32_bf16(wf[t][q], zf[m][q], acc[m][t], 0, 0, 0);

  // Epilogue 1: acc (+ b1/2) -> LDS (reuse ldsF as 32 x 256 bf16). C/D
  // layout: col=l15 -> node row nl, row=quad*4+reg -> output o. The o-range
  // [s*64+t*16+quad*4, +4) maps to b1[o & 127] (same bias for U and V halves).
  bf16* epi = reinterpret_cast<bf16*>(ldsF);
#pragma unroll
  for (int m = 0; m < 2; ++m) {
    const int nl = m * 16 + l15;
#pragma unroll
    for (int t = 0; t < 4; ++t) {
      const int o = s * 64 + t * 16 + quad * 4;
      const float4 bv = *reinterpret_cast<const float4*>(bias1 + (o & (H - 1)));
      ushort4 st;
      st.x = (unsigned short)bfbits(acc[m][t][0] + 0.5f * bv.x);
      st.y = (unsigned short)bfbits(acc[m][t][1] + 0.5f * bv.y);
      st.z = (unsigned short)bfbits(acc[m][t][2] + 0.5f * bv.z);
      st.w = (unsigned short)bfbits(acc[m][t][3] + 0.5f * bv.w);
      *reinterpret_cast<ushort4*>(epi + nl * 256 + o) = st;
    }
  }
  __syncthreads();

  // Epilogue 2: coalesced stores; each instr = 4 node-rows x 256B contiguous.
#pragma unroll
  for (int half = 0; half < 2; ++half) {
    bf16* base = half ? V : U;
#pragma unroll
    for (int it = 0; it < 2; ++it) {
      const int nl = s * 8 + it * 4 + (lane >> 4);
      const int oc = (lane & 15) * 8;
      const short8 v = *reinterpret_cast<const short8*>(epi + nl * 256 + half * H + oc);
      const int n = nodebase + nl;
      if (n < N_NODES)
        *reinterpret_cast<short8*>(base + (size_t)n * H + oc) = v;
    }
  }
}

// h = relu(U'+V') pairs; sum += h·w2 (b1 already baked into U', V').
static __device__ __forceinline__ void acc2(unsigned u, unsigned v,
                                            float w2lo, float w2hi, float& sum) {
  const float ulo = __uint_as_float(u << 16);
  const float uhi = __uint_as_float(u & 0xffff0000u);
  const float vlo = __uint_as_float(v << 16);
  const float vhi = __uint_as_float(v & 0xffff0000u);
  float h0 = fmaxf(ulo + vlo, 0.f);
  float h1 = fmaxf(uhi + vhi, 0.f);
  sum = fmaf(h0, w2lo, sum);
  sum = fmaf(h1, w2hi, sum);
}

// Phase 2: flat decode, one wave per 64-edge chunk (grid-stride). 8-lane
// group per edge; lane owns 16 hidden elems = 2x16B U + 2x16B V gathers.
// Per half: issue ALL 16 gathers, then sched_barrier(0) pins them above the
// compute loop — the compiler must keep 16 results live (R0's VGPR=60
// showed it otherwise sinks loads, leaving only ~5 in flight). ~100 VGPR,
// fits 4 waves/EU; 1024 blocks = exactly resident at 4 blocks/CU.
__global__ __launch_bounds__(256, 4) void edge_decode(
    const int* __restrict__ eidx, const bf16* __restrict__ Ub,
    const bf16* __restrict__ Vb, const float* __restrict__ W2,
    const float* __restrict__ bias2, float* __restrict__ out) {
  const int lane = threadIdx.x & 63;
  const int e8 = lane & 7;

  float w2r[16];
  const float4* wp = reinterpret_cast<const float4*>(W2 + e8 * 16);
#pragma unroll
  for (int q = 0; q < 4; ++q) {
    const float4 wv = wp[q];
    w2r[q * 4 + 0] = wv.x; w2r[q * 4 + 1] = wv.y;
    w2r[q * 4 + 2] = wv.z; w2r[q * 4 + 3] = wv.w;
  }
  const float b2 = bias2[0];

  const uint4* U4 = reinterpret_cast<const uint4*>(Ub);  // row = 16 uint4
  const uint4* V4 = reinterpret_cast<const uint4*>(Vb);

  const int wid0 = blockIdx.x * 4 + (int)(threadIdx.x >> 6);
  for (int c = wid0; c < N_EDGES / 64; c += 4096) {  // 4096 = grid waves
    const int chunk = c * 64;
    const int src = eidx[chunk + lane];
    const int dst = eidx[N_EDGES + chunk + lane];

    float res = 0.f;
#pragma unroll
    for (int half = 0; half < 2; ++half) {
      uint4 ua[4], ub[4], va[4], vb[4];
      // Issue all 16 gather loads for 4 edges...
#pragma unroll
      for (int j = 0; j < 4; ++j) {
        const int i = half * 4 + j;
        const int sl = (lane & 56) | i;
        const int s_i = __shfl(src, sl);
        const int d_i = __shfl(dst, sl);
        const uint4* up = U4 + (size_t)s_i * 16 + e8 * 2;
        const uint4* vp = V4 + (size_t)d_i * 16 + e8 * 2;
        ua[j] = up[0]; ub[j] = up[1];
        va[j] = vp[0]; vb[j] = vp[1];
      }
      // ...and pin them above the consume loop (no sinking / serializing).
      __builtin_amdgcn_sched_barrier(0);
#pragma unroll
      for (int j = 0; j < 4; ++j) {
        const int i = half * 4 + j;
        float sum = 0.f;
        acc2(ua[j].x, va[j].x, w2r[0],  w2r[1],  sum);
        acc2(ua[j].y, va[j].y, w2r[2],  w2r[3],  sum);
        acc2(ua[j].z, va[j].z, w2r[4],  w2r[5],  sum);
        acc2(ua[j].w, va[j].w, w2r[6],  w2r[7],  sum);
        acc2(ub[j].x, vb[j].x, w2r[8],  w2r[9],  sum);
        acc2(ub[j].y, vb[j].y, w2r[10], w2r[11], sum);
        acc2(ub[j].z, vb[j].z, w2r[12], w2r[13], sum);
        acc2(ub[j].w, vb[j].w, w2r[14], w2r[15], sum);
        sum += __shfl_xor(sum, 1);
        sum += __shfl_xor(sum, 2);
        sum += __shfl_xor(sum, 4);
        if (e8 == i) res = sum + b2;
      }
    }
    out[chunk + lane] = res;  // coalesced 4 B/lane
  }
}

extern "C" void kernel_launch(void* const* d_in, const int* in_sizes, int n_in,
                              void* d_out, int out_size, void* d_ws, size_t ws_size,
                              hipStream_t stream) {
  const float* z     = (const float*)d_in[0];
  const float* W1    = (const float*)d_in[1];
  const float* bias1 = (const float*)d_in[2];
  const float* W2    = (const float*)d_in[3];
  const float* bias2 = (const float*)d_in[4];
  const int*   eidx  = (const int*)d_in[5];
  float* out = (float*)d_out;

  bf16* U  = (bf16*)d_ws;                // [N_NODES, H]
  bf16* V  = U + (size_t)N_NODES * H;    // [N_NODES, H]
  bf16* Wb = V + (size_t)N_NODES * H;    // [256, H] (64 KB)

  // W convert: 4096 units / 256 = 16 blocks (~1.5 us).
  hipLaunchKernelGGL(w_to_bf16, dim3(16), dim3(256), 0, stream, W1, Wb);
  // Phase 1: 1563 blocks x 4 waves; block = 32-node tile, wave = 64-output
  // split; b1/2 folded into both U and V.
  hipLaunchKernelGGL(precompute_uv, dim3((N_NODES + 31) / 32), dim3(256), 0,
                     stream, z, Wb, bias1, U, V);
  // Phase 2: 1024 blocks (exactly resident), 4096 waves grid-striding
  // 10000 chunks of 64 edges.
  hipLaunchKernelGGL(edge_decode, dim3(1024), dim3(256), 0, stream,
                     eidx, U, V, W2, bias2, out);
}

// Round 6
// 137.556 us; speedup vs baseline: 1.4733x; 1.0111x over previous
//
#include <hip/hip_runtime.h>
#include <hip/hip_bf16.h>

// EdgeDecoder: out[e] = W2 @ relu(W1 @ [z[src]; z[dst]] + b1) + b2
// Restructure: W1 = [W1a | W1b] over the concat ->
//   U[n] = W1a @ z[n] + b1/2, V[n] = W1b @ z[n] + b1/2   (precomputed, MFMA)
//   out[e] = dot(relu(U[src]+V[dst]), W2) + b2
//
// R13: R5 showed sched_barrier(0) does NOT pin loads (VGPR stayed 60 — IR
// sinking bypasses the machine-sched fence) and 1024 grid-stride blocks cut
// resident waves vs R0's 2500-block flood (occ 29% => decode 42.6us, worse
// than R0's 36.5). Fix: R0's exact decode shape (2500 blocks, one chunk per
// wave) + a REAL anchor: empty asm volatile consuming one component of each
// of the 16 gather results right after issue. The results are asm operands,
// so all 16 loads must be issued before one vmcnt drain point — per-wave
// in-flight goes ~5 -> 16 (VGPR ~100-110, still 4 waves/EU). b1 stays
// folded into U,V (decode VALU -13%). Predicted: decode 24-28us, total
// ~124-128; if decode unchanged ~36-42 => fabric-BW ceiling at ~3.3TB/s
// confirmed => roofline (fills 88.6us are a fixed floor).

#define N_NODES 50000
#define N_EDGES 640000
#define H 128

using bf16 = __hip_bfloat16;
typedef __attribute__((ext_vector_type(8))) short short8;  // 8 bf16, 4 VGPRs
typedef __attribute__((ext_vector_type(4))) float f32x4;   // MFMA acc

#define GLD_LDS16(g, l)                                                     \
  __builtin_amdgcn_global_load_lds(                                         \
      (const __attribute__((address_space(1))) void*)(g),                   \
      (__attribute__((address_space(3))) void*)(l), 16, 0, 0)

static __device__ __forceinline__ short bfbits(float x) {
  __hip_bfloat16 h = __float2bfloat16(x);
  return *reinterpret_cast<short*>(&h);
}

static __device__ __forceinline__ short8 pack8(float4 a, float4 b) {
  short8 r;
  r[0] = bfbits(a.x); r[1] = bfbits(a.y); r[2] = bfbits(a.z); r[3] = bfbits(a.w);
  r[4] = bfbits(b.x); r[5] = bfbits(b.y); r[6] = bfbits(b.z); r[7] = bfbits(b.w);
  return r;
}

// Tiny: Wb[o][k] (bf16, A-frag row layout) from fp32 W1. o<128 -> W1[o][k],
// o>=128 -> W1[o-128][128+k]. 4096 units of 8 elems -> 16 blocks.
__global__ __launch_bounds__(256) void w_to_bf16(const float* __restrict__ W1,
                                                 bf16* __restrict__ Wb) {
  const int u = blockIdx.x * 256 + threadIdx.x;
  const int o = u >> 4, k8 = (u & 15) * 8;
  const float4* src = reinterpret_cast<const float4*>(
      W1 + (size_t)(o & (H - 1)) * (2 * H) + (o >> 7) * H + k8);
  *reinterpret_cast<short8*>(Wb + (size_t)o * H + k8) = pack8(src[0], src[1]);
}

#define HP 136  // padded bf16 LDS row stride (272B): breaks 256B-stride conflicts

// Phase 1: block = 4 waves = one 32-node tile; wave s owns outputs
// [s*64, s*64+64). fp32 z staged via global_load_lds DMA, one LDS pass
// converts to bf16, frags via ds_read_b128, 32 MFMAs, LDS-transposed
// coalesced epilogue. Adds 0.5*b1[o] before the bf16 round, so decode can
// skip the bias add entirely (U+V restores b1).
__global__ __launch_bounds__(256) void precompute_uv(
    const float* __restrict__ z, const bf16* __restrict__ Wb,
    const float* __restrict__ bias1, bf16* __restrict__ U,
    bf16* __restrict__ V) {
  __shared__ float ldsF[32 * H];       // 16 KB: fp32 z stage, later epilogue tile
  __shared__ bf16 ldsH[32 * HP];       // 8.5 KB: padded bf16 z tile
  const int tid = threadIdx.x;
  const int lane = tid & 63;
  const int s = tid >> 6;  // wave id = o-split 0..3
  const int l15 = lane & 15, quad = lane >> 4;
  const int nodebase = blockIdx.x * 32;

  // Stage: wave s DMAs rows [s*8, s*8+8) of the tile; 4 x 1KB contiguous.
  {
    int r0 = nodebase + s * 8;
    if (r0 > N_NODES - 8) r0 = N_NODES - 8;  // tail clamp (stores guarded)
    const float* gsrc = z + (size_t)r0 * H + lane * 4;
    float* ldst = ldsF + s * 8 * H;  // + lane*16B implicit
#pragma unroll
    for (int j = 0; j < 4; ++j) GLD_LDS16(gsrc + j * 256, ldst + j * 256);
  }

  // W-frags from global bf16 (64 KB, L2-hot) — overlaps the DMA.
  short8 wf[4][4];  // [o-tile][k-step]
#pragma unroll
  for (int t = 0; t < 4; ++t) {
    const bf16* wp = Wb + (size_t)(s * 64 + t * 16 + l15) * H + quad * 8;
#pragma unroll
    for (int q = 0; q < 4; ++q)
      wf[t][q] = *reinterpret_cast<const short8*>(wp + q * 32);
  }

  __syncthreads();  // DMA + conversion-input visible

  // Convert: thread handles 16 consecutive fp32 of row (tid>>3).
  {
    const int row = tid >> 3, off = (tid & 7) * 16;
    const float4* fp = reinterpret_cast<const float4*>(ldsF + row * H + off);
    const float4 a = fp[0], b = fp[1], c = fp[2], d = fp[3];
    *reinterpret_cast<short8*>(&ldsH[row * HP + off]) = pack8(a, b);
    *reinterpret_cast<short8*>(&ldsH[row * HP + off + 8]) = pack8(c, d);
  }
  __syncthreads();

  // z-frags from LDS + 32 back-to-back MFMAs.
  short8 zf[2][4];
#pragma unroll
  for (int m = 0; m < 2; ++m)
#pragma unroll
    for (int q = 0; q < 4; ++q)
      zf[m][q] = *reinterpret_cast<const short8*>(
          &ldsH[(m * 16 + l15) * HP + quad * 8 + q * 32]);

  f32x4 acc[2][4] = {};
#pragma unroll
  for (int m = 0; m < 2; ++m)
#pragma unroll
    for (int t = 0; t < 4; ++t)
#pragma unroll
      for (int q = 0; q < 4; ++q)
        acc[m][t] =
            __builtin_amdgcn_mfma_f32_16x16x32_bf16(wf[t][q], zf[m][q], acc[m][t], 0, 0, 0);

  // Epilogue 1: acc (+ b1/2) -> LDS (reuse ldsF as 32 x 256 bf16). C/D
  // layout: col=l15 -> node row nl, row=quad*4+reg -> output o. o-range
  // maps to b1[o & 127] (same bias for U and V halves).
  bf16* epi = reinterpret_cast<bf16*>(ldsF);
#pragma unroll
  for (int m = 0; m < 2; ++m) {
    const int nl = m * 16 + l15;
#pragma unroll
    for (int t = 0; t < 4; ++t) {
      const int o = s * 64 + t * 16 + quad * 4;
      const float4 bv = *reinterpret_cast<const float4*>(bias1 + (o & (H - 1)));
      ushort4 st;
      st.x = (unsigned short)bfbits(acc[m][t][0] + 0.5f * bv.x);
      st.y = (unsigned short)bfbits(acc[m][t][1] + 0.5f * bv.y);
      st.z = (unsigned short)bfbits(acc[m][t][2] + 0.5f * bv.z);
      st.w = (unsigned short)bfbits(acc[m][t][3] + 0.5f * bv.w);
      *reinterpret_cast<ushort4*>(epi + nl * 256 + o) = st;
    }
  }
  __syncthreads();

  // Epilogue 2: coalesced stores; each instr = 4 node-rows x 256B contiguous.
#pragma unroll
  for (int half = 0; half < 2; ++half) {
    bf16* base = half ? V : U;
#pragma unroll
    for (int it = 0; it < 2; ++it) {
      const int nl = s * 8 + it * 4 + (lane >> 4);
      const int oc = (lane & 15) * 8;
      const short8 v = *reinterpret_cast<const short8*>(epi + nl * 256 + half * H + oc);
      const int n = nodebase + nl;
      if (n < N_NODES)
        *reinterpret_cast<short8*>(base + (size_t)n * H + oc) = v;
    }
  }
}

// h = relu(U'+V') pairs; sum += h·w2 (b1 already baked into U', V').
static __device__ __forceinline__ void acc2(unsigned u, unsigned v,
                                            float w2lo, float w2hi, float& sum) {
  const float ulo = __uint_as_float(u << 16);
  const float uhi = __uint_as_float(u & 0xffff0000u);
  const float vlo = __uint_as_float(v << 16);
  const float vhi = __uint_as_float(v & 0xffff0000u);
  float h0 = fmaxf(ulo + vlo, 0.f);
  float h1 = fmaxf(uhi + vhi, 0.f);
  sum = fmaf(h0, w2lo, sum);
  sum = fmaf(h1, w2hi, sum);
}

// Phase 2: R0's exact shape — 2500 blocks, one wave per 64-edge chunk, no
// grid-stride. 8-lane group per edge; lane owns 16 hidden elems = 2x16B U +
// 2x16B V gathers, batched 4 edges deep per half. After issuing the 16
// gathers, an empty asm volatile CONSUMES one component of each result:
// all 16 loads must be issued before the single vmcnt drain at the asm, so
// the compiler cannot interleave compute with partial waits (R0/R5 compiled
// to VGPR=60 = only ~5 loads in flight). sched_barrier keeps compute below.
__global__ __launch_bounds__(256, 4) void edge_decode(
    const int* __restrict__ eidx, const bf16* __restrict__ Ub,
    const bf16* __restrict__ Vb, const float* __restrict__ W2,
    const float* __restrict__ bias2, float* __restrict__ out) {
  const int lane = threadIdx.x & 63;
  const int e8 = lane & 7;
  const int w = blockIdx.x * 4 + (int)(threadIdx.x >> 6);
  const int chunk = w * 64;

  float w2r[16];
  const float4* wp = reinterpret_cast<const float4*>(W2 + e8 * 16);
#pragma unroll
  for (int q = 0; q < 4; ++q) {
    const float4 wv = wp[q];
    w2r[q * 4 + 0] = wv.x; w2r[q * 4 + 1] = wv.y;
    w2r[q * 4 + 2] = wv.z; w2r[q * 4 + 3] = wv.w;
  }
  const float b2 = bias2[0];

  const int src = eidx[chunk + lane];
  const int dst = eidx[N_EDGES + chunk + lane];
  const uint4* U4 = reinterpret_cast<const uint4*>(Ub);  // row = 16 uint4
  const uint4* V4 = reinterpret_cast<const uint4*>(Vb);

  float res = 0.f;
#pragma unroll
  for (int half = 0; half < 2; ++half) {
    uint4 ua[4], ub[4], va[4], vb[4];
    // Issue all 16 gather loads for 4 edges...
#pragma unroll
    for (int j = 0; j < 4; ++j) {
      const int i = half * 4 + j;
      const int sl = (lane & 56) | i;
      const int s_i = __shfl(src, sl);
      const int d_i = __shfl(dst, sl);
      const uint4* up = U4 + (size_t)s_i * 16 + e8 * 2;
      const uint4* vp = V4 + (size_t)d_i * 16 + e8 * 2;
      ua[j] = up[0]; ub[j] = up[1];
      va[j] = vp[0]; vb[j] = vp[1];
    }
    // ...anchor all 16 results HERE: they become asm operands, so every
    // load is issued before one vmcnt drain — 16 in flight, not ~5.
    asm volatile("" ::
        "v"(ua[0].x), "v"(ua[1].x), "v"(ua[2].x), "v"(ua[3].x),
        "v"(ub[0].x), "v"(ub[1].x), "v"(ub[2].x), "v"(ub[3].x),
        "v"(va[0].x), "v"(va[1].x), "v"(va[2].x), "v"(va[3].x),
        "v"(vb[0].x), "v"(vb[1].x), "v"(vb[2].x), "v"(vb[3].x));
    __builtin_amdgcn_sched_barrier(0);
#pragma unroll
    for (int j = 0; j < 4; ++j) {
      const int i = half * 4 + j;
      float sum = 0.f;
      acc2(ua[j].x, va[j].x, w2r[0],  w2r[1],  sum);
      acc2(ua[j].y, va[j].y, w2r[2],  w2r[3],  sum);
      acc2(ua[j].z, va[j].z, w2r[4],  w2r[5],  sum);
      acc2(ua[j].w, va[j].w, w2r[6],  w2r[7],  sum);
      acc2(ub[j].x, vb[j].x, w2r[8],  w2r[9],  sum);
      acc2(ub[j].y, vb[j].y, w2r[10], w2r[11], sum);
      acc2(ub[j].z, vb[j].z, w2r[12], w2r[13], sum);
      acc2(ub[j].w, vb[j].w, w2r[14], w2r[15], sum);
      sum += __shfl_xor(sum, 1);
      sum += __shfl_xor(sum, 2);
      sum += __shfl_xor(sum, 4);
      if (e8 == i) res = sum + b2;
    }
  }
  out[chunk + lane] = res;  // coalesced 4 B/lane
}

extern "C" void kernel_launch(void* const* d_in, const int* in_sizes, int n_in,
                              void* d_out, int out_size, void* d_ws, size_t ws_size,
                              hipStream_t stream) {
  const float* z     = (const float*)d_in[0];
  const float* W1    = (const float*)d_in[1];
  const float* bias1 = (const float*)d_in[2];
  const float* W2    = (const float*)d_in[3];
  const float* bias2 = (const float*)d_in[4];
  const int*   eidx  = (const int*)d_in[5];
  float* out = (float*)d_out;

  bf16* U  = (bf16*)d_ws;                // [N_NODES, H]
  bf16* V  = U + (size_t)N_NODES * H;    // [N_NODES, H]
  bf16* Wb = V + (size_t)N_NODES * H;    // [256, H] (64 KB)

  // W convert: 4096 units / 256 = 16 blocks (~1.5 us).
  hipLaunchKernelGGL(w_to_bf16, dim3(16), dim3(256), 0, stream, W1, Wb);
  // Phase 1: 1563 blocks x 4 waves; block = 32-node tile, wave = 64-output
  // split; b1/2 folded into both U and V.
  hipLaunchKernelGGL(precompute_uv, dim3((N_NODES + 31) / 32), dim3(256), 0,
                     stream, z, Wb, bias1, U, V);
  // Phase 2: 2500 blocks x 4 waves, one 64-edge chunk each (R0 shape).
  hipLaunchKernelGGL(edge_decode, dim3(N_EDGES / 64 / 4), dim3(256), 0, stream,
                     eidx, U, V, W2, bias2, out);
}